// Round 12
// baseline (245.127 us; speedup 1.0000x reference)
//
#include <hip/hip_runtime.h>
#include <hip/hip_bf16.h>

typedef __attribute__((ext_vector_type(8))) short bf16x8;
typedef __attribute__((ext_vector_type(4))) float f32x4;
typedef __attribute__((ext_vector_type(16))) float f32x16;

#define NPTS 8192
#define KNB  16
#define CG   10
#define CIN  128
#define CC   256
#define COUT 256
#define PB   8        // points per block (8 waves)
#define A2_LD 400     // a2S pitch in bf16 (800 B -> 8-dword bank stagger per row)

// d_ws layout (bytes)
#define WSA_OFF 0         // w_attn frags: 256x256 bf16 = 131072
#define WSB_OFF 131072    // W2 frags:    384x256 bf16 = 196608
#define DD_OFF  327680    // dd[256] fp32 = 1024
#define WN_OFF  328704    // w_n frags (an-folded, K=32 zero-pad): 8x64x8 bf16 = 8192
#define DN_OFF  336896    // dn_n[128] fp32 = 512
#define FB_OFF  524288    // featbf: 32768 x 128 bf16 = 8388608
#define WS_FB   (FB_OFF + 8388608ull)

#define LOG2E 1.4426950408889634f

__device__ __forceinline__ short f2bs(float x) {
    __hip_bfloat16 h = __float2bfloat16(x);
    return *reinterpret_cast<short*>(&h);
}

// ---------------- pre: featbf cvt + weight fragment packing ----------------
// wsA packed for mfma_f32_32x32x16_bf16: frag (kt 0..15, nt 0..7); lane l: hi=l>>5,
// c5=l&31; elem j: B[k = kt*16 + hi*8 + j][col = nt*32 + c5], log2e-folded.
__global__ __launch_bounds__(256) void lfa_pre(
    const float* __restrict__ feature,
    const float* __restrict__ w_attn,
    const float* __restrict__ w_n, const float* __restrict__ b_n,
    const float* __restrict__ g_n, const float* __restrict__ beta_n,
    const float* __restrict__ rm_n, const float* __restrict__ rv_n,
    const float* __restrict__ w_o, const float* __restrict__ b_o,
    const float* __restrict__ g_o, const float* __restrict__ beta_o,
    const float* __restrict__ rm_o, const float* __restrict__ rv_o,
    const float* __restrict__ w_s, const float* __restrict__ b_s,
    const float* __restrict__ g_s, const float* __restrict__ beta_s,
    const float* __restrict__ rm_s, const float* __restrict__ rv_s,
    __hip_bfloat16* __restrict__ featbf,
    __hip_bfloat16* __restrict__ wsA, __hip_bfloat16* __restrict__ wsB,
    float* __restrict__ dd,
    __hip_bfloat16* __restrict__ wsN, float* __restrict__ dnw,
    int use_fb)
{
    const int b = blockIdx.x, tid = threadIdx.x;
    if (b < 2048) {                      // featbf: fp32 -> bf16, 8 elems/thread
        if (!use_fb) return;
        size_t gid = (size_t)b * 256 + tid;
        const float4* src = (const float4*)(feature + gid * 8);
        float4 x = src[0], y = src[1];
        bf16x8 v;
        v[0] = f2bs(x.x); v[1] = f2bs(x.y); v[2] = f2bs(x.z); v[3] = f2bs(x.w);
        v[4] = f2bs(y.x); v[5] = f2bs(y.y); v[6] = f2bs(y.z); v[7] = f2bs(y.w);
        *(bf16x8*)(featbf + gid * 8) = v;
        return;
    }
    int gid = (b - 2048) * 256 + tid;    // weight packing
    if (gid < 8192) {                    // w_attn: 128 frags for 32x32x16 (kt 0..15, nt 0..7)
        int f = gid >> 6, l = gid & 63;
        int kt = f >> 3, nt = f & 7, hi = l >> 5, c5 = l & 31;
        int col = nt * 32 + c5;
        bf16x8 v;
        #pragma unroll
        for (int j = 0; j < 8; ++j)
            v[j] = f2bs(w_attn[(kt * 16 + hi * 8 + j) * CC + col] * LOG2E);
        *(bf16x8*)(wsA + (size_t)gid * 8) = v;
    } else if (gid < 8192 + 12288) {     // W2 = [w_s*a_s ; w_o*a_o]: 192 frags (16x16x32)
        int g2 = gid - 8192;
        int f = g2 >> 6, l = g2 & 63;
        int kt = f >> 4, nt = f & 15, q = l >> 4, c0 = l & 15;
        int c = nt * 16 + c0;
        float as = g_s[c] * rsqrtf(rv_s[c] + 1e-5f);
        float ao = g_o[c] * rsqrtf(rv_o[c] + 1e-5f);
        bf16x8 v;
        #pragma unroll
        for (int j = 0; j < 8; ++j) {
            int r = kt * 32 + q * 8 + j;
            float x = (r < CIN) ? w_s[r * COUT + c] * as
                                : w_o[(r - CIN) * COUT + c] * ao;
            v[j] = f2bs(x);
        }
        *(bf16x8*)(wsB + (size_t)g2 * 8) = v;
    } else if (gid < 20736) {            // dd[c]
        int c = gid - 20480;
        float as = g_s[c] * rsqrtf(rv_s[c] + 1e-5f);
        float ao = g_o[c] * rsqrtf(rv_o[c] + 1e-5f);
        dd[c] = beta_s[c] + (b_s[c] - rm_s[c]) * as
              + beta_o[c] + (b_o[c] - rm_o[c]) * ao;
    } else if (gid < 21248) {            // w_n frags: an folded, K zero-pad to 32
        int g3 = gid - 20736;
        int nt = g3 >> 6, l = g3 & 63;
        int q = l >> 4, c0 = l & 15;
        int n = nt * 16 + c0;
        float an = g_n[n] * rsqrtf(rv_n[n] + 1e-5f);
        bf16x8 v;
        #pragma unroll
        for (int j = 0; j < 8; ++j) {
            int k = q * 8 + j;
            v[j] = (k < CG) ? f2bs(w_n[k * 128 + n] * an) : (short)0;
        }
        *(bf16x8*)(wsN + (size_t)g3 * 8) = v;
    } else if (gid < 21376) {            // dn_n[c]
        int c = gid - 21248;
        float an = g_n[c] * rsqrtf(rv_n[c] + 1e-5f);
        dnw[c] = beta_n[c] + (b_n[c] - rm_n[c]) * an;
    }
}

// ---------------- main fused kernel: PB=8 points per block, 8 waves ----------------
// r11 lesson: 2x2 split's doubled wsA L2 traffic > its LDS saving -> reverted to
// r9's 1x8 (wave w owns cols 32w..32w+31, 4 m-tiles). r12: deeper catS swizzle
// sw2(row) = (row&7) ^ ((row>>3)&3). Old sw used only row&7; with 512 B row pitch
// every row starts at bank 0, so phase-1's 4 lanes with equal c5&7 (rows 8 apart)
// hit the same banks -> structural 4-way conflict. The extra 2 XOR bits separate
// them (af conflict-free; 0c writes 4-way -> 2-way = free per m136).
__global__ __launch_bounds__(512, 4) void lfa_main(
    const float* __restrict__ feature,   // [B,N,CIN] fp32
    const float* __restrict__ rawn,      // [B,N,K,CG]
    const int*   __restrict__ nidx,      // [B,N,K]
    const __hip_bfloat16* __restrict__ wsA,
    const __hip_bfloat16* __restrict__ wsB,
    const float* __restrict__ dd,
    const __hip_bfloat16* __restrict__ wsN,
    const float* __restrict__ dnw,
    const __hip_bfloat16* __restrict__ featbf,
    int use_fb,
    float* __restrict__ out)             // [B,N,COUT]
{
    // catS: [128 rows][256 bf16], XOR-swizzled 16B chunks: chunk_phys = chunk ^ sw2(row)
    __shared__ __align__(16) __hip_bfloat16 catS[128 * 256];  // 65536 B
    __shared__ __align__(16) __hip_bfloat16 a2S[PB * A2_LD];  // 6400 B

    const int tid  = threadIdx.x;
    const int lane = tid & 63;
    const int w    = tid >> 6;     // wave id 0..7
    const int q    = lane >> 4;    // quad 0..3
    const int c0   = lane & 15;
    const int hi   = lane >> 5;    // half 0..1 (32x32 MFMA)
    const int c5   = lane & 31;    // col-in-tile (32x32 MFMA)
    const long long base0 = (long long)blockIdx.x * PB;   // identity mapping
    const long long bIdx  = base0 >> 13;                  // batch index (N=8192)

    // ---- phase 0a: this wave's neighbor-MLP A-fragment (point w, neighbor c0)
    bf16x8 am;
    {
        bf16x8 v;
        #pragma unroll
        for (int j = 0; j < 8; ++j) v[j] = 0;
        const float* rb = rawn + ((base0 + w) * KNB + c0) * CG;
        if (q == 0) {
            float2 a0 = *(const float2*)(rb + 0), a1 = *(const float2*)(rb + 2);
            float2 a2 = *(const float2*)(rb + 4), a3 = *(const float2*)(rb + 6);
            v[0] = f2bs(a0.x); v[1] = f2bs(a0.y); v[2] = f2bs(a1.x); v[3] = f2bs(a1.y);
            v[4] = f2bs(a2.x); v[5] = f2bs(a2.y); v[6] = f2bs(a3.x); v[7] = f2bs(a3.y);
        } else if (q == 1) {
            float2 a4 = *(const float2*)(rb + 8);
            v[0] = f2bs(a4.x); v[1] = f2bs(a4.y);
        }
        am = v;
    }

    // ---- phase 0b: center features -> a2S rows 0..7, cols 0..127
    if (use_fb) {
        if (tid < 128) {
            int p = tid >> 4, ch = tid & 15;
            *(bf16x8*)&a2S[p * A2_LD + ch * 8] =
                *(const bf16x8*)(featbf + (base0 + p) * CIN + ch * 8);
        }
    } else {
        int p = tid >> 6, cc = (tid & 63) * 2;
        const float* src = feature + (base0 + p) * CIN + cc;
        a2S[p * A2_LD + cc]     = __float2bfloat16(src[0]);
        a2S[p * A2_LD + cc + 1] = __float2bfloat16(src[1]);
    }
    // ---- phase 0c: gather neighbor features -> catS cols 0..127 (128 rows)
    {
        int row = tid >> 2, qd = tid & 3;            // 128 rows x 4 quarters
        int ridx = nidx[base0 * KNB + row];          // 4-way dup -> L2 broadcast
        int sw = (row & 7) ^ ((row >> 3) & 3);       // sw2
        if (use_fb) {
            const bf16x8* src = (const bf16x8*)(featbf + (bIdx * NPTS + ridx) * CIN + qd * 32);
            #pragma unroll
            for (int j = 0; j < 4; ++j)
                *(bf16x8*)&catS[row * 256 + (((qd * 4 + j) ^ sw) << 3)] = src[j];
        } else {
            const float4* src = (const float4*)(feature + (bIdx * NPTS + ridx) * CIN + qd * 32);
            #pragma unroll
            for (int j = 0; j < 4; ++j) {
                float4 x = src[2 * j], y = src[2 * j + 1];
                bf16x8 v;
                v[0] = f2bs(x.x); v[1] = f2bs(x.y); v[2] = f2bs(x.z); v[3] = f2bs(x.w);
                v[4] = f2bs(y.x); v[5] = f2bs(y.y); v[6] = f2bs(y.z); v[7] = f2bs(y.w);
                *(bf16x8*)&catS[row * 256 + (((qd * 4 + j) ^ sw) << 3)] = v;
            }
        }
    }

    // ---- phase 0d: neighbor MLP via MFMA -> catS cols 128..255, rows 16w..16w+15
    {
        const f32x4 vz = {0.f, 0.f, 0.f, 0.f};
        #pragma unroll
        for (int nt = 0; nt < 8; ++nt) {
            bf16x8 wnb = *(const bf16x8*)(wsN + (size_t)((nt * 64 + lane) * 8));
            f32x4 cm = __builtin_amdgcn_mfma_f32_16x16x32_bf16(am, wnb, vz, 0, 0, 0);
            int c = nt * 16 + c0;            // MLP out channel 0..127
            float dnv = dnw[c];
            int col = CIN + c;
            #pragma unroll
            for (int r = 0; r < 4; ++r) {
                float y = cm[r] + dnv;
                y = (y >= 0.f) ? y : 0.2f * y;
                int row = w * 16 + q * 4 + r;
                int sw = (row & 7) ^ ((row >> 3) & 3);
                catS[row * 256 + ((((col >> 3) ^ sw) << 3)) + (col & 7)] =
                    __float2bfloat16(y);
            }
        }
    }
    __syncthreads();

    // ---- phase 1: logits GEMM  C[128 x 256] = cat[128 x 256] @ w_attn[256 x 256]
    // 32x32x16 MFMA, 1x8 split (r9): wave w owns cols 32w..32w+31, 4 m-tiles.
    // A frag: row = m*32 + c5; sw2 = (c5&7)^((c5>>3)&3) is m-invariant (m*4 = 0 mod 4).
    f32x16 acc32[4];
    #pragma unroll
    for (int m = 0; m < 4; ++m)
        #pragma unroll
        for (int r = 0; r < 16; ++r) acc32[m][r] = 0.f;

    const int swc = (c5 & 7) ^ ((c5 >> 3) & 3);
    #pragma unroll
    for (int kt = 0; kt < 16; ++kt) {
        bf16x8 bfr = *(const bf16x8*)(wsA + (size_t)(((kt * 8 + w) * 64 + lane) * 8));
        int chunk = (kt * 2 + hi) ^ swc;
        #pragma unroll
        for (int m = 0; m < 4; ++m) {
            bf16x8 af = *(const bf16x8*)&catS[(m * 32 + c5) * 256 + (chunk << 3)];
            acc32[m] = __builtin_amdgcn_mfma_f32_32x32x16_bf16(af, bfr, acc32[m], 0, 0, 0);
        }
    }

    // ---- phase 2: per-channel softmax over k (exp2; log2e in wsA) + pooling
    // 32x32 C layout: col = c5, row = (reg&3) + 8*(reg>>2) + 4*hi.
    // sw2 for row = mt*32 + rowin: (rowin&7) = (reg&3)+4*hi; ((row>>3)&3) = reg>>2.
    {
        const int c = w * 32 + c5;
        #pragma unroll
        for (int m = 0; m < 4; ++m) {
            float sA = 0.f, sB = 0.f, pA = 0.f, pB = 0.f;
            #pragma unroll
            for (int reg = 0; reg < 16; ++reg) {
                float e = __builtin_amdgcn_exp2f(acc32[m][reg]);
                int rowin = (reg & 3) + 8 * (reg >> 2) + 4 * hi;
                int sw = ((reg & 3) + 4 * hi) ^ (reg >> 2);
                int cvo = ((((c >> 3) ^ sw) << 3) + (c & 7));
                float cv = __bfloat162float(catS[(m * 32 + rowin) * 256 + cvo]);
                if (reg < 8) { sA += e; pA += e * cv; }
                else         { sB += e; pB += e * cv; }
            }
            sA += __shfl_xor(sA, 32);
            sB += __shfl_xor(sB, 32);
            pA += __shfl_xor(pA, 32);
            pB += __shfl_xor(pB, 32);
            if (hi == 0)
                a2S[(2 * m) * A2_LD + CIN + c] =
                    __float2bfloat16(pA * __builtin_amdgcn_rcpf(sA));
            else
                a2S[(2 * m + 1) * A2_LD + CIN + c] =
                    __float2bfloat16(pB * __builtin_amdgcn_rcpf(sB));
        }
    }
    __syncthreads();

    // ---- phase 3: out GEMM  [8 x 256] = [feat|pooled][8 x 384] @ W2[384 x 256]
    const f32x4 vzero = {0.f, 0.f, 0.f, 0.f};
    f32x4 acc2[2];
    acc2[0] = vzero; acc2[1] = vzero;
    #pragma unroll
    for (int kt = 0; kt < 12; ++kt) {
        bf16x8 a = *(const bf16x8*)&a2S[(c0 & 7) * A2_LD + kt * 32 + q * 8];
        bf16x8 b0 = *(const bf16x8*)(wsB + (size_t)(((kt * 16 + 2 * w + 0) * 64 + lane) * 8));
        bf16x8 b1 = *(const bf16x8*)(wsB + (size_t)(((kt * 16 + 2 * w + 1) * 64 + lane) * 8));
        acc2[0] = __builtin_amdgcn_mfma_f32_16x16x32_bf16(a, b0, acc2[0], 0, 0, 0);
        acc2[1] = __builtin_amdgcn_mfma_f32_16x16x32_bf16(a, b1, acc2[1], 0, 0, 0);
    }
    // stage to LDS (reuse catS as fp32 [8][256]), then fully-coalesced float4 store
    float* outS = (float*)catS;
    if (q < 2) {                       // rows q*4+r = points 0..7 exactly
        #pragma unroll
        for (int i = 0; i < 2; ++i) {
            int c = (2 * w + i) * 16 + c0;
            float dv = dd[c];
            #pragma unroll
            for (int r = 0; r < 4; ++r) {
                int p = q * 4 + r;
                float y = acc2[i][r] + dv;
                y = (y >= 0.f) ? y : 0.2f * y;
                outS[p * 256 + c] = y;
            }
        }
    }
    __syncthreads();
    {
        int p = tid >> 6, c4 = (tid & 63) * 4;
        *(float4*)(out + (base0 + p) * COUT + c4) = *(const float4*)&outS[p * 256 + c4];
    }
}

extern "C" void kernel_launch(void* const* d_in, const int* in_sizes, int n_in,
                              void* d_out, int out_size, void* d_ws, size_t ws_size,
                              hipStream_t stream) {
    const float* feature = (const float*)d_in[0];
    const float* rawn    = (const float*)d_in[1];
    const int*   nidx    = (const int*)d_in[2];
    const float* w_n     = (const float*)d_in[3];
    const float* b_n     = (const float*)d_in[4];
    const float* g_n     = (const float*)d_in[5];
    const float* beta_n  = (const float*)d_in[6];
    const float* rm_n    = (const float*)d_in[7];
    const float* rv_n    = (const float*)d_in[8];
    const float* w_attn  = (const float*)d_in[9];
    const float* w_o     = (const float*)d_in[10];
    const float* b_o     = (const float*)d_in[11];
    const float* g_o     = (const float*)d_in[12];
    const float* beta_o  = (const float*)d_in[13];
    const float* rm_o    = (const float*)d_in[14];
    const float* rv_o    = (const float*)d_in[15];
    const float* w_s     = (const float*)d_in[16];
    const float* b_s     = (const float*)d_in[17];
    const float* g_s     = (const float*)d_in[18];
    const float* beta_s  = (const float*)d_in[19];
    const float* rm_s    = (const float*)d_in[20];
    const float* rv_s    = (const float*)d_in[21];
    float* out = (float*)d_out;

    __hip_bfloat16* wsA    = (__hip_bfloat16*)((char*)d_ws + WSA_OFF);
    __hip_bfloat16* wsB    = (__hip_bfloat16*)((char*)d_ws + WSB_OFF);
    float*          ddp    = (float*)((char*)d_ws + DD_OFF);
    __hip_bfloat16* wsN    = (__hip_bfloat16*)((char*)d_ws + WN_OFF);
    float*          dnw    = (float*)((char*)d_ws + DN_OFF);
    __hip_bfloat16* featbf = (__hip_bfloat16*)((char*)d_ws + FB_OFF);
    const int use_fb = (ws_size >= WS_FB) ? 1 : 0;

    lfa_pre<<<2132, 256, 0, stream>>>(
        feature, w_attn,
        w_n, b_n, g_n, beta_n, rm_n, rv_n,
        w_o, b_o, g_o, beta_o, rm_o, rv_o,
        w_s, b_s, g_s, beta_s, rm_s, rv_s,
        featbf, wsA, wsB, ddp, wsN, dnw, use_fb);

    const int nblocks = (4 * NPTS) / PB;   // 4096
    lfa_main<<<nblocks, 512, 0, stream>>>(
        feature, rawn, nidx,
        wsA, wsB, ddp, wsN, dnw, featbf, use_fb, out);
}

// Round 14
// 232.320 us; speedup vs baseline: 1.0551x; 1.0551x over previous
//
#include <hip/hip_runtime.h>
#include <hip/hip_bf16.h>

typedef __attribute__((ext_vector_type(8))) short bf16x8;
typedef __attribute__((ext_vector_type(4))) float f32x4;
typedef __attribute__((ext_vector_type(16))) float f32x16;

#define NPTS 8192
#define KNB  16
#define CG   10
#define CIN  128
#define CC   256
#define COUT 256
#define PB   8        // points per block (8 waves)
#define A2_LD 400     // a2S pitch in bf16 (800 B -> 8-dword bank stagger per row)

// d_ws layout (bytes)
#define WSA_OFF 0         // w_attn frags: 256x256 bf16 = 131072
#define WSB_OFF 131072    // W2 frags:    384x256 bf16 = 196608
#define DD_OFF  327680    // dd[256] fp32 = 1024
#define WN_OFF  328704    // w_n frags (an-folded, K=32 zero-pad): 8x64x8 bf16 = 8192
#define DN_OFF  336896    // dn_n[128] fp32 = 512
#define FB_OFF  524288    // featbf: 32768 x 128 bf16 = 8388608
#define WS_FB   (FB_OFF + 8388608ull)

#define LOG2E 1.4426950408889634f

__device__ __forceinline__ short f2bs(float x) {
    __hip_bfloat16 h = __float2bfloat16(x);
    return *reinterpret_cast<short*>(&h);
}

// async global->LDS DMA, 16 B per lane; LDS dest = wave-uniform base + lane*16 (linear!)
__device__ __forceinline__ void gload_lds16(const void* g, void* l) {
    __builtin_amdgcn_global_load_lds(
        (const __attribute__((address_space(1))) unsigned int*)g,
        (__attribute__((address_space(3))) unsigned int*)l,
        16, 0, 0);
}

// ---------------- pre: featbf cvt + weight fragment packing ----------------
// wsA packed for mfma_f32_32x32x16_bf16: frag (kt 0..15, nt 0..7); lane l: hi=l>>5,
// c5=l&31; elem j: B[k = kt*16 + hi*8 + j][col = nt*32 + c5], log2e-folded.
__global__ __launch_bounds__(256) void lfa_pre(
    const float* __restrict__ feature,
    const float* __restrict__ w_attn,
    const float* __restrict__ w_n, const float* __restrict__ b_n,
    const float* __restrict__ g_n, const float* __restrict__ beta_n,
    const float* __restrict__ rm_n, const float* __restrict__ rv_n,
    const float* __restrict__ w_o, const float* __restrict__ b_o,
    const float* __restrict__ g_o, const float* __restrict__ beta_o,
    const float* __restrict__ rm_o, const float* __restrict__ rv_o,
    const float* __restrict__ w_s, const float* __restrict__ b_s,
    const float* __restrict__ g_s, const float* __restrict__ beta_s,
    const float* __restrict__ rm_s, const float* __restrict__ rv_s,
    __hip_bfloat16* __restrict__ featbf,
    __hip_bfloat16* __restrict__ wsA, __hip_bfloat16* __restrict__ wsB,
    float* __restrict__ dd,
    __hip_bfloat16* __restrict__ wsN, float* __restrict__ dnw,
    int use_fb)
{
    const int b = blockIdx.x, tid = threadIdx.x;
    if (b < 2048) {                      // featbf: fp32 -> bf16, 8 elems/thread
        if (!use_fb) return;
        size_t gid = (size_t)b * 256 + tid;
        const float4* src = (const float4*)(feature + gid * 8);
        float4 x = src[0], y = src[1];
        bf16x8 v;
        v[0] = f2bs(x.x); v[1] = f2bs(x.y); v[2] = f2bs(x.z); v[3] = f2bs(x.w);
        v[4] = f2bs(y.x); v[5] = f2bs(y.y); v[6] = f2bs(y.z); v[7] = f2bs(y.w);
        *(bf16x8*)(featbf + gid * 8) = v;
        return;
    }
    int gid = (b - 2048) * 256 + tid;    // weight packing
    if (gid < 8192) {                    // w_attn: 128 frags for 32x32x16 (kt 0..15, nt 0..7)
        int f = gid >> 6, l = gid & 63;
        int kt = f >> 3, nt = f & 7, hi = l >> 5, c5 = l & 31;
        int col = nt * 32 + c5;
        bf16x8 v;
        #pragma unroll
        for (int j = 0; j < 8; ++j)
            v[j] = f2bs(w_attn[(kt * 16 + hi * 8 + j) * CC + col] * LOG2E);
        *(bf16x8*)(wsA + (size_t)gid * 8) = v;
    } else if (gid < 8192 + 12288) {     // W2 = [w_s*a_s ; w_o*a_o]: 192 frags (16x16x32)
        int g2 = gid - 8192;
        int f = g2 >> 6, l = g2 & 63;
        int kt = f >> 4, nt = f & 15, q = l >> 4, c0 = l & 15;
        int c = nt * 16 + c0;
        float as = g_s[c] * rsqrtf(rv_s[c] + 1e-5f);
        float ao = g_o[c] * rsqrtf(rv_o[c] + 1e-5f);
        bf16x8 v;
        #pragma unroll
        for (int j = 0; j < 8; ++j) {
            int r = kt * 32 + q * 8 + j;
            float x = (r < CIN) ? w_s[r * COUT + c] * as
                                : w_o[(r - CIN) * COUT + c] * ao;
            v[j] = f2bs(x);
        }
        *(bf16x8*)(wsB + (size_t)g2 * 8) = v;
    } else if (gid < 20736) {            // dd[c]
        int c = gid - 20480;
        float as = g_s[c] * rsqrtf(rv_s[c] + 1e-5f);
        float ao = g_o[c] * rsqrtf(rv_o[c] + 1e-5f);
        dd[c] = beta_s[c] + (b_s[c] - rm_s[c]) * as
              + beta_o[c] + (b_o[c] - rm_o[c]) * ao;
    } else if (gid < 21248) {            // w_n frags: an folded, K zero-pad to 32
        int g3 = gid - 20736;
        int nt = g3 >> 6, l = g3 & 63;
        int q = l >> 4, c0 = l & 15;
        int n = nt * 16 + c0;
        float an = g_n[n] * rsqrtf(rv_n[n] + 1e-5f);
        bf16x8 v;
        #pragma unroll
        for (int j = 0; j < 8; ++j) {
            int k = q * 8 + j;
            v[j] = (k < CG) ? f2bs(w_n[k * 128 + n] * an) : (short)0;
        }
        *(bf16x8*)(wsN + (size_t)g3 * 8) = v;
    } else if (gid < 21376) {            // dn_n[c]
        int c = gid - 21248;
        float an = g_n[c] * rsqrtf(rv_n[c] + 1e-5f);
        dnw[c] = beta_n[c] + (b_n[c] - rm_n[c]) * an;
    }
}

// ---------------- main fused kernel: PB=8 points per block, 8 waves ----------------
// r13 audit: global_load_lds writes lane*16 LINEAR, so a 512 B-pitch catS with only
// 256 B gathered per row mis-maps lane groups (g16=1 would clobber row r's MLP half).
// Fix: split catS into featS[128][128] (gathered, 256 B rows -- DMA-exact) and
// mlpS[128][128] (MLP outputs). Phase-1 kt<8 -> featS, kt>=8 -> mlpS (compile-time
// under unroll); phase-2 w<4 -> featS, w>=4 -> mlpS (wave-uniform). sw1 swizzle
// folded into the per-lane GLOBAL address (m173 pattern); layout algebra unchanged.
__global__ __launch_bounds__(512, 4) void lfa_main(
    const float* __restrict__ feature,   // [B,N,CIN] fp32
    const float* __restrict__ rawn,      // [B,N,K,CG]
    const int*   __restrict__ nidx,      // [B,N,K]
    const __hip_bfloat16* __restrict__ wsA,
    const __hip_bfloat16* __restrict__ wsB,
    const float* __restrict__ dd,
    const __hip_bfloat16* __restrict__ wsN,
    const float* __restrict__ dnw,
    const __hip_bfloat16* __restrict__ featbf,
    int use_fb,
    float* __restrict__ out)             // [B,N,COUT]
{
    // featS: gathered neighbor features, [128 rows][128 bf16], 16B chunks swizzled
    // chunk_phys = chunk ^ (row&7). mlpS: neighbor-MLP outputs, same pitch/swizzle.
    __shared__ __align__(16) __hip_bfloat16 featS[128 * 128];  // 32768 B
    __shared__ __align__(16) __hip_bfloat16 mlpS[128 * 128];   // 32768 B
    __shared__ __align__(16) __hip_bfloat16 a2S[PB * A2_LD];   // 6400 B

    const int tid  = threadIdx.x;
    const int lane = tid & 63;
    const int w    = tid >> 6;     // wave id 0..7
    const int q    = lane >> 4;    // quad 0..3
    const int c0   = lane & 15;
    const int hi   = lane >> 5;    // half 0..1 (32x32 MFMA)
    const int c5   = lane & 31;    // col-in-tile (32x32 MFMA)
    const long long base0 = (long long)blockIdx.x * PB;   // identity mapping
    const long long bIdx  = base0 >> 13;                  // batch index (N=8192)

    // ---- phase 0c-DMA: gather neighbor features -> featS rows 16w..16w+15
    // One DMA stages 4 rows (16 lanes x 16 B = one 256 B row). Swizzle folded into
    // the per-lane global chunk select; LDS dest linear.
    if (use_fb) {
        #pragma unroll
        for (int j = 0; j < 4; ++j) {
            int row  = w * 16 + j * 4 + (lane >> 4);
            int ridx = nidx[base0 * KNB + row];
            const __hip_bfloat16* gsrc = featbf + (bIdx * NPTS + ridx) * CIN
                                       + (((lane & 15) ^ (row & 7)) << 3);
            gload_lds16(gsrc, featS + (size_t)(w * 16 + j * 4) * 128);
        }
    }

    // ---- phase 0a: this wave's neighbor-MLP A-fragment (point w, neighbor c0)
    bf16x8 am;
    {
        bf16x8 v;
        #pragma unroll
        for (int j = 0; j < 8; ++j) v[j] = 0;
        const float* rb = rawn + ((base0 + w) * KNB + c0) * CG;
        if (q == 0) {
            float2 a0 = *(const float2*)(rb + 0), a1 = *(const float2*)(rb + 2);
            float2 a2 = *(const float2*)(rb + 4), a3 = *(const float2*)(rb + 6);
            v[0] = f2bs(a0.x); v[1] = f2bs(a0.y); v[2] = f2bs(a1.x); v[3] = f2bs(a1.y);
            v[4] = f2bs(a2.x); v[5] = f2bs(a2.y); v[6] = f2bs(a3.x); v[7] = f2bs(a3.y);
        } else if (q == 1) {
            float2 a4 = *(const float2*)(rb + 8);
            v[0] = f2bs(a4.x); v[1] = f2bs(a4.y);
        }
        am = v;
    }

    // ---- phase 0b: center features -> a2S rows 0..7, cols 0..127
    if (use_fb) {
        if (tid < 128) {
            int p = tid >> 4, ch = tid & 15;
            *(bf16x8*)&a2S[p * A2_LD + ch * 8] =
                *(const bf16x8*)(featbf + (base0 + p) * CIN + ch * 8);
        }
    } else {
        int p = tid >> 6, cc = (tid & 63) * 2;
        const float* src = feature + (base0 + p) * CIN + cc;
        a2S[p * A2_LD + cc]     = __float2bfloat16(src[0]);
        a2S[p * A2_LD + cc + 1] = __float2bfloat16(src[1]);
    }
    // ---- phase 0c fallback (no featbf workspace): manual fp32 gather
    if (!use_fb) {
        int row = tid >> 2, qd = tid & 3;            // 128 rows x 4 quarters
        int ridx = nidx[base0 * KNB + row];
        int sw = row & 7;
        const float4* src = (const float4*)(feature + (bIdx * NPTS + ridx) * CIN + qd * 32);
        #pragma unroll
        for (int j = 0; j < 4; ++j) {
            float4 x = src[2 * j], y = src[2 * j + 1];
            bf16x8 v;
            v[0] = f2bs(x.x); v[1] = f2bs(x.y); v[2] = f2bs(x.z); v[3] = f2bs(x.w);
            v[4] = f2bs(y.x); v[5] = f2bs(y.y); v[6] = f2bs(y.z); v[7] = f2bs(y.w);
            *(bf16x8*)&featS[row * 128 + (((qd * 4 + j) ^ sw) << 3)] = v;
        }
    }

    // ---- phase 0d: neighbor MLP via MFMA -> mlpS rows 16w..16w+15
    {
        const f32x4 vz = {0.f, 0.f, 0.f, 0.f};
        #pragma unroll
        for (int nt = 0; nt < 8; ++nt) {
            bf16x8 wnb = *(const bf16x8*)(wsN + (size_t)((nt * 64 + lane) * 8));
            f32x4 cm = __builtin_amdgcn_mfma_f32_16x16x32_bf16(am, wnb, vz, 0, 0, 0);
            int c = nt * 16 + c0;            // MLP out channel 0..127
            float dnv = dnw[c];
            #pragma unroll
            for (int r = 0; r < 4; ++r) {
                float y = cm[r] + dnv;
                y = (y >= 0.f) ? y : 0.2f * y;
                int row = w * 16 + q * 4 + r;
                mlpS[row * 128 + ((((c >> 3) ^ (row & 7)) << 3)) + (c & 7)] =
                    __float2bfloat16(y);
            }
        }
    }
    __syncthreads();   // drains DMA vmcnt + LDS writes

    // ---- phase 1: logits GEMM  C[128 x 256] = cat[128 x 256] @ w_attn[256 x 256]
    // 32x32x16 MFMA, 1x8 split: wave w owns cols 32w..32w+31, 4 m-tiles.
    // A frag row = m*32 + c5; k-chunks 0..15 from featS, 16..31 from mlpS.
    f32x16 acc32[4];
    #pragma unroll
    for (int m = 0; m < 4; ++m)
        #pragma unroll
        for (int r = 0; r < 16; ++r) acc32[m][r] = 0.f;

    const int swc = c5 & 7;
    #pragma unroll
    for (int kt = 0; kt < 16; ++kt) {
        bf16x8 bfr = *(const bf16x8*)(wsA + (size_t)(((kt * 8 + w) * 64 + lane) * 8));
        int chunk = ((kt * 2 + hi) & 15) ^ swc;       // within-region chunk 0..15
        const __hip_bfloat16* base = (kt < 8) ? featS : mlpS;
        #pragma unroll
        for (int m = 0; m < 4; ++m) {
            bf16x8 af = *(const bf16x8*)&base[(m * 32 + c5) * 128 + (chunk << 3)];
            acc32[m] = __builtin_amdgcn_mfma_f32_32x32x16_bf16(af, bfr, acc32[m], 0, 0, 0);
        }
    }

    // ---- phase 2: per-channel softmax over k (exp2; log2e in wsA) + pooling
    // 32x32 C layout: col = c5, row = (reg&3) + 8*(reg>>2) + 4*hi.
    // Tile m covers points {2m, 2m+1}: regs 0..7 -> pt 2m, 8..15 -> pt 2m+1.
    // cat col c = w*32+c5: w<4 -> featS (c<128), w>=4 -> mlpS (c-128).
    {
        const int c = w * 32 + c5;
        const int cl = c & 127;
        const __hip_bfloat16* catBase = (w < 4) ? featS : mlpS;
        #pragma unroll
        for (int m = 0; m < 4; ++m) {
            float sA = 0.f, sB = 0.f, pA = 0.f, pB = 0.f;
            #pragma unroll
            for (int reg = 0; reg < 16; ++reg) {
                float e = __builtin_amdgcn_exp2f(acc32[m][reg]);
                int rowin = (reg & 3) + 8 * (reg >> 2) + 4 * hi;
                int cvo = ((((cl >> 3) ^ ((reg & 3) + 4 * hi)) << 3) + (cl & 7));
                float cv = __bfloat162float(catBase[(m * 32 + rowin) * 128 + cvo]);
                if (reg < 8) { sA += e; pA += e * cv; }
                else         { sB += e; pB += e * cv; }
            }
            sA += __shfl_xor(sA, 32);
            sB += __shfl_xor(sB, 32);
            pA += __shfl_xor(pA, 32);
            pB += __shfl_xor(pB, 32);
            if (hi == 0)
                a2S[(2 * m) * A2_LD + CIN + c] =
                    __float2bfloat16(pA * __builtin_amdgcn_rcpf(sA));
            else
                a2S[(2 * m + 1) * A2_LD + CIN + c] =
                    __float2bfloat16(pB * __builtin_amdgcn_rcpf(sB));
        }
    }
    __syncthreads();

    // ---- phase 3: out GEMM  [8 x 256] = [feat|pooled][8 x 384] @ W2[384 x 256]
    const f32x4 vzero = {0.f, 0.f, 0.f, 0.f};
    f32x4 acc2[2];
    acc2[0] = vzero; acc2[1] = vzero;
    #pragma unroll
    for (int kt = 0; kt < 12; ++kt) {
        bf16x8 a = *(const bf16x8*)&a2S[(c0 & 7) * A2_LD + kt * 32 + q * 8];
        bf16x8 b0 = *(const bf16x8*)(wsB + (size_t)(((kt * 16 + 2 * w + 0) * 64 + lane) * 8));
        bf16x8 b1 = *(const bf16x8*)(wsB + (size_t)(((kt * 16 + 2 * w + 1) * 64 + lane) * 8));
        acc2[0] = __builtin_amdgcn_mfma_f32_16x16x32_bf16(a, b0, acc2[0], 0, 0, 0);
        acc2[1] = __builtin_amdgcn_mfma_f32_16x16x32_bf16(a, b1, acc2[1], 0, 0, 0);
    }
    // stage to LDS (reuse featS as fp32 [8][256]), then fully-coalesced float4 store
    float* outS = (float*)featS;
    if (q < 2) {                       // rows q*4+r = points 0..7 exactly
        #pragma unroll
        for (int i = 0; i < 2; ++i) {
            int c = (2 * w + i) * 16 + c0;
            float dv = dd[c];
            #pragma unroll
            for (int r = 0; r < 4; ++r) {
                int p = q * 4 + r;
                float y = acc2[i][r] + dv;
                y = (y >= 0.f) ? y : 0.2f * y;
                outS[p * 256 + c] = y;
            }
        }
    }
    __syncthreads();
    {
        int p = tid >> 6, c4 = (tid & 63) * 4;
        *(float4*)(out + (base0 + p) * COUT + c4) = *(const float4*)&outS[p * 256 + c4];
    }
}

extern "C" void kernel_launch(void* const* d_in, const int* in_sizes, int n_in,
                              void* d_out, int out_size, void* d_ws, size_t ws_size,
                              hipStream_t stream) {
    const float* feature = (const float*)d_in[0];
    const float* rawn    = (const float*)d_in[1];
    const int*   nidx    = (const int*)d_in[2];
    const float* w_n     = (const float*)d_in[3];
    const float* b_n     = (const float*)d_in[4];
    const float* g_n     = (const float*)d_in[5];
    const float* beta_n  = (const float*)d_in[6];
    const float* rm_n    = (const float*)d_in[7];
    const float* rv_n    = (const float*)d_in[8];
    const float* w_attn  = (const float*)d_in[9];
    const float* w_o     = (const float*)d_in[10];
    const float* b_o     = (const float*)d_in[11];
    const float* g_o     = (const float*)d_in[12];
    const float* beta_o  = (const float*)d_in[13];
    const float* rm_o    = (const float*)d_in[14];
    const float* rv_o    = (const float*)d_in[15];
    const float* w_s     = (const float*)d_in[16];
    const float* b_s     = (const float*)d_in[17];
    const float* g_s     = (const float*)d_in[18];
    const float* beta_s  = (const float*)d_in[19];
    const float* rm_s    = (const float*)d_in[20];
    const float* rv_s    = (const float*)d_in[21];
    float* out = (float*)d_out;

    __hip_bfloat16* wsA    = (__hip_bfloat16*)((char*)d_ws + WSA_OFF);
    __hip_bfloat16* wsB    = (__hip_bfloat16*)((char*)d_ws + WSB_OFF);
    float*          ddp    = (float*)((char*)d_ws + DD_OFF);
    __hip_bfloat16* wsN    = (__hip_bfloat16*)((char*)d_ws + WN_OFF);
    float*          dnw    = (float*)((char*)d_ws + DN_OFF);
    __hip_bfloat16* featbf = (__hip_bfloat16*)((char*)d_ws + FB_OFF);
    const int use_fb = (ws_size >= WS_FB) ? 1 : 0;

    lfa_pre<<<2132, 256, 0, stream>>>(
        feature, w_attn,
        w_n, b_n, g_n, beta_n, rm_n, rv_n,
        w_o, b_o, g_o, beta_o, rm_o, rv_o,
        w_s, b_s, g_s, beta_s, rm_s, rv_s,
        featbf, wsA, wsB, ddp, wsN, dnw, use_fb);

    const int nblocks = (4 * NPTS) / PB;   // 4096
    lfa_main<<<nblocks, 512, 0, stream>>>(
        feature, rawn, nidx,
        wsA, wsB, ddp, wsN, dnw, featbf, use_fb, out);
}

// Round 15
// 230.634 us; speedup vs baseline: 1.0628x; 1.0073x over previous
//
#include <hip/hip_runtime.h>
#include <hip/hip_bf16.h>

typedef __attribute__((ext_vector_type(8))) short bf16x8;
typedef __attribute__((ext_vector_type(4))) short short4v;
typedef __attribute__((ext_vector_type(4))) float f32x4;
typedef __attribute__((ext_vector_type(16))) float f32x16;

#define NPTS 8192
#define KNB  16
#define CG   10
#define CIN  128
#define CC   256
#define COUT 256
#define PB   8        // points per block (8 waves)
#define A2_LD 400     // a2S pitch in bf16 (800 B -> 8-dword bank stagger per row)

// d_ws layout (bytes)
#define WSA_OFF 0         // w_attn frags: 256x256 bf16 = 131072
#define WSB_OFF 131072    // W2 frags:    384x256 bf16 = 196608
#define DD_OFF  327680    // dd[256] fp32 = 1024
#define WN_OFF  328704    // w_n frags (an-folded, K=32 zero-pad): 8x64x8 bf16 = 8192
#define DN_OFF  336896    // dn_n[128] fp32 = 512
#define FB_OFF  524288    // featbf: 32768 x 128 bf16 = 8388608
#define WS_FB   (FB_OFF + 8388608ull)

#define LOG2E 1.4426950408889634f

__device__ __forceinline__ short f2bs(float x) {
    __hip_bfloat16 h = __float2bfloat16(x);
    return *reinterpret_cast<short*>(&h);
}

// async global->LDS DMA, 16 B per lane; LDS dest = wave-uniform base + lane*16 (linear!)
__device__ __forceinline__ void gload_lds16(const void* g, void* l) {
    __builtin_amdgcn_global_load_lds(
        (const __attribute__((address_space(1))) unsigned int*)g,
        (__attribute__((address_space(3))) unsigned int*)l,
        16, 0, 0);
}

// ---------------- pre: featbf cvt + weight fragment packing ----------------
// wsA packed for mfma_f32_32x32x16_bf16: frag (kt 0..15, nt 0..7); lane l: hi=l>>5,
// c5=l&31; elem j: B[k = kt*16 + hi*8 + j][col = nt*32 + c5], log2e-folded.
__global__ __launch_bounds__(256) void lfa_pre(
    const float* __restrict__ feature,
    const float* __restrict__ w_attn,
    const float* __restrict__ w_n, const float* __restrict__ b_n,
    const float* __restrict__ g_n, const float* __restrict__ beta_n,
    const float* __restrict__ rm_n, const float* __restrict__ rv_n,
    const float* __restrict__ w_o, const float* __restrict__ b_o,
    const float* __restrict__ g_o, const float* __restrict__ beta_o,
    const float* __restrict__ rm_o, const float* __restrict__ rv_o,
    const float* __restrict__ w_s, const float* __restrict__ b_s,
    const float* __restrict__ g_s, const float* __restrict__ beta_s,
    const float* __restrict__ rm_s, const float* __restrict__ rv_s,
    __hip_bfloat16* __restrict__ featbf,
    __hip_bfloat16* __restrict__ wsA, __hip_bfloat16* __restrict__ wsB,
    float* __restrict__ dd,
    __hip_bfloat16* __restrict__ wsN, float* __restrict__ dnw,
    int use_fb)
{
    const int b = blockIdx.x, tid = threadIdx.x;
    if (b < 2048) {                      // featbf: fp32 -> bf16, 8 elems/thread
        if (!use_fb) return;
        size_t gid = (size_t)b * 256 + tid;
        const float4* src = (const float4*)(feature + gid * 8);
        float4 x = src[0], y = src[1];
        bf16x8 v;
        v[0] = f2bs(x.x); v[1] = f2bs(x.y); v[2] = f2bs(x.z); v[3] = f2bs(x.w);
        v[4] = f2bs(y.x); v[5] = f2bs(y.y); v[6] = f2bs(y.z); v[7] = f2bs(y.w);
        *(bf16x8*)(featbf + gid * 8) = v;
        return;
    }
    int gid = (b - 2048) * 256 + tid;    // weight packing
    if (gid < 8192) {                    // w_attn: 128 frags for 32x32x16 (kt 0..15, nt 0..7)
        int f = gid >> 6, l = gid & 63;
        int kt = f >> 3, nt = f & 7, hi = l >> 5, c5 = l & 31;
        int col = nt * 32 + c5;
        bf16x8 v;
        #pragma unroll
        for (int j = 0; j < 8; ++j)
            v[j] = f2bs(w_attn[(kt * 16 + hi * 8 + j) * CC + col] * LOG2E);
        *(bf16x8*)(wsA + (size_t)gid * 8) = v;
    } else if (gid < 8192 + 12288) {     // W2 = [w_s*a_s ; w_o*a_o]: 192 frags (16x16x32)
        int g2 = gid - 8192;
        int f = g2 >> 6, l = g2 & 63;
        int kt = f >> 4, nt = f & 15, q = l >> 4, c0 = l & 15;
        int c = nt * 16 + c0;
        float as = g_s[c] * rsqrtf(rv_s[c] + 1e-5f);
        float ao = g_o[c] * rsqrtf(rv_o[c] + 1e-5f);
        bf16x8 v;
        #pragma unroll
        for (int j = 0; j < 8; ++j) {
            int r = kt * 32 + q * 8 + j;
            float x = (r < CIN) ? w_s[r * COUT + c] * as
                                : w_o[(r - CIN) * COUT + c] * ao;
            v[j] = f2bs(x);
        }
        *(bf16x8*)(wsB + (size_t)g2 * 8) = v;
    } else if (gid < 20736) {            // dd[c]
        int c = gid - 20480;
        float as = g_s[c] * rsqrtf(rv_s[c] + 1e-5f);
        float ao = g_o[c] * rsqrtf(rv_o[c] + 1e-5f);
        dd[c] = beta_s[c] + (b_s[c] - rm_s[c]) * as
              + beta_o[c] + (b_o[c] - rm_o[c]) * ao;
    } else if (gid < 21248) {            // w_n frags: an folded, K zero-pad to 32
        int g3 = gid - 20736;
        int nt = g3 >> 6, l = g3 & 63;
        int q = l >> 4, c0 = l & 15;
        int n = nt * 16 + c0;
        float an = g_n[n] * rsqrtf(rv_n[n] + 1e-5f);
        bf16x8 v;
        #pragma unroll
        for (int j = 0; j < 8; ++j) {
            int k = q * 8 + j;
            v[j] = (k < CG) ? f2bs(w_n[k * 128 + n] * an) : (short)0;
        }
        *(bf16x8*)(wsN + (size_t)g3 * 8) = v;
    } else if (gid < 21376) {            // dn_n[c]
        int c = gid - 21248;
        float an = g_n[c] * rsqrtf(rv_n[c] + 1e-5f);
        dnw[c] = beta_n[c] + (b_n[c] - rm_n[c]) * an;
    }
}

// ---------------- main fused kernel: PB=8 points per block, 8 waves ----------------
// r14: DMA gather verified (133 us). r15: 0d MFMA operand swap -- mfma(wnb, am)
// computes D[channel][neighbor] (wsN is already A=Wn^T, am is already B=raw^T in
// the m89-verified lane layouts). Lane then holds 4 CONSECUTIVE channels at one
// catS row -> one packed b64 write (was 4 scalar u16), one float4 dnw load.
// lrelu as fmax(y, 0.2y) (valid both signs).
__global__ __launch_bounds__(512, 4) void lfa_main(
    const float* __restrict__ feature,   // [B,N,CIN] fp32
    const float* __restrict__ rawn,      // [B,N,K,CG]
    const int*   __restrict__ nidx,      // [B,N,K]
    const __hip_bfloat16* __restrict__ wsA,
    const __hip_bfloat16* __restrict__ wsB,
    const float* __restrict__ dd,
    const __hip_bfloat16* __restrict__ wsN,
    const float* __restrict__ dnw,
    const __hip_bfloat16* __restrict__ featbf,
    int use_fb,
    float* __restrict__ out)             // [B,N,COUT]
{
    // featS: gathered neighbor features, [128 rows][128 bf16], 16B chunks swizzled
    // chunk_phys = chunk ^ (row&7). mlpS: neighbor-MLP outputs, same pitch/swizzle.
    __shared__ __align__(16) __hip_bfloat16 featS[128 * 128];  // 32768 B
    __shared__ __align__(16) __hip_bfloat16 mlpS[128 * 128];   // 32768 B
    __shared__ __align__(16) __hip_bfloat16 a2S[PB * A2_LD];   // 6400 B

    const int tid  = threadIdx.x;
    const int lane = tid & 63;
    const int w    = tid >> 6;     // wave id 0..7
    const int q    = lane >> 4;    // quad 0..3
    const int c0   = lane & 15;
    const int hi   = lane >> 5;    // half 0..1 (32x32 MFMA)
    const int c5   = lane & 31;    // col-in-tile (32x32 MFMA)
    const long long base0 = (long long)blockIdx.x * PB;   // identity mapping
    const long long bIdx  = base0 >> 13;                  // batch index (N=8192)

    // ---- phase 0c-DMA: gather neighbor features -> featS rows 16w..16w+15
    // One DMA stages 4 rows (16 lanes x 16 B = one 256 B row). Swizzle folded into
    // the per-lane global chunk select; LDS dest linear.
    if (use_fb) {
        #pragma unroll
        for (int j = 0; j < 4; ++j) {
            int row  = w * 16 + j * 4 + (lane >> 4);
            int ridx = nidx[base0 * KNB + row];
            const __hip_bfloat16* gsrc = featbf + (bIdx * NPTS + ridx) * CIN
                                       + (((lane & 15) ^ (row & 7)) << 3);
            gload_lds16(gsrc, featS + (size_t)(w * 16 + j * 4) * 128);
        }
    }

    // ---- phase 0a: this wave's neighbor-MLP A-fragment (point w, neighbor c0)
    bf16x8 am;
    {
        bf16x8 v;
        #pragma unroll
        for (int j = 0; j < 8; ++j) v[j] = 0;
        const float* rb = rawn + ((base0 + w) * KNB + c0) * CG;
        if (q == 0) {
            float2 a0 = *(const float2*)(rb + 0), a1 = *(const float2*)(rb + 2);
            float2 a2 = *(const float2*)(rb + 4), a3 = *(const float2*)(rb + 6);
            v[0] = f2bs(a0.x); v[1] = f2bs(a0.y); v[2] = f2bs(a1.x); v[3] = f2bs(a1.y);
            v[4] = f2bs(a2.x); v[5] = f2bs(a2.y); v[6] = f2bs(a3.x); v[7] = f2bs(a3.y);
        } else if (q == 1) {
            float2 a4 = *(const float2*)(rb + 8);
            v[0] = f2bs(a4.x); v[1] = f2bs(a4.y);
        }
        am = v;
    }

    // ---- phase 0b: center features -> a2S rows 0..7, cols 0..127
    if (use_fb) {
        if (tid < 128) {
            int p = tid >> 4, ch = tid & 15;
            *(bf16x8*)&a2S[p * A2_LD + ch * 8] =
                *(const bf16x8*)(featbf + (base0 + p) * CIN + ch * 8);
        }
    } else {
        int p = tid >> 6, cc = (tid & 63) * 2;
        const float* src = feature + (base0 + p) * CIN + cc;
        a2S[p * A2_LD + cc]     = __float2bfloat16(src[0]);
        a2S[p * A2_LD + cc + 1] = __float2bfloat16(src[1]);
    }
    // ---- phase 0c fallback (no featbf workspace): manual fp32 gather
    if (!use_fb) {
        int row = tid >> 2, qd = tid & 3;            // 128 rows x 4 quarters
        int ridx = nidx[base0 * KNB + row];
        int sw = row & 7;
        const float4* src = (const float4*)(feature + (bIdx * NPTS + ridx) * CIN + qd * 32);
        #pragma unroll
        for (int j = 0; j < 4; ++j) {
            float4 x = src[2 * j], y = src[2 * j + 1];
            bf16x8 v;
            v[0] = f2bs(x.x); v[1] = f2bs(x.y); v[2] = f2bs(x.z); v[3] = f2bs(x.w);
            v[4] = f2bs(y.x); v[5] = f2bs(y.y); v[6] = f2bs(y.z); v[7] = f2bs(y.w);
            *(bf16x8*)&featS[row * 128 + (((qd * 4 + j) ^ sw) << 3)] = v;
        }
    }

    // ---- phase 0d: neighbor MLP via MFMA (operands swapped) -> mlpS rows 16w..16w+15
    // D[row=channel][col=neighbor]: lane (q,c0) holds channels nt*16+q*4+{0..3} at
    // catS row w*16+c0 -> packed b64 write per nt.
    {
        const f32x4 vz = {0.f, 0.f, 0.f, 0.f};
        const int row = w * 16 + c0;
        #pragma unroll
        for (int nt = 0; nt < 8; ++nt) {
            bf16x8 wnb = *(const bf16x8*)(wsN + (size_t)((nt * 64 + lane) * 8));
            f32x4 cm = __builtin_amdgcn_mfma_f32_16x16x32_bf16(wnb, am, vz, 0, 0, 0);
            int chan = nt * 16 + q * 4;          // channels chan..chan+3
            float4 dnv4 = *(const float4*)(dnw + chan);
            short4v v;
            {
                float y0 = cm[0] + dnv4.x; y0 = fmaxf(y0, 0.2f * y0);
                float y1 = cm[1] + dnv4.y; y1 = fmaxf(y1, 0.2f * y1);
                float y2 = cm[2] + dnv4.z; y2 = fmaxf(y2, 0.2f * y2);
                float y3 = cm[3] + dnv4.w; y3 = fmaxf(y3, 0.2f * y3);
                v[0] = f2bs(y0); v[1] = f2bs(y1); v[2] = f2bs(y2); v[3] = f2bs(y3);
            }
            int chunk = (chan >> 3) ^ (row & 7);
            *(short4v*)&mlpS[row * 128 + (chunk << 3) + ((q & 1) << 2)] = v;
        }
    }
    __syncthreads();   // drains DMA vmcnt + LDS writes

    // ---- phase 1: logits GEMM  C[128 x 256] = cat[128 x 256] @ w_attn[256 x 256]
    // 32x32x16 MFMA, 1x8 split: wave w owns cols 32w..32w+31, 4 m-tiles.
    // A frag row = m*32 + c5; k-chunks 0..15 from featS, 16..31 from mlpS.
    f32x16 acc32[4];
    #pragma unroll
    for (int m = 0; m < 4; ++m)
        #pragma unroll
        for (int r = 0; r < 16; ++r) acc32[m][r] = 0.f;

    const int swc = c5 & 7;
    #pragma unroll
    for (int kt = 0; kt < 16; ++kt) {
        bf16x8 bfr = *(const bf16x8*)(wsA + (size_t)(((kt * 8 + w) * 64 + lane) * 8));
        int chunk = ((kt * 2 + hi) & 15) ^ swc;       // within-region chunk 0..15
        const __hip_bfloat16* base = (kt < 8) ? featS : mlpS;
        #pragma unroll
        for (int m = 0; m < 4; ++m) {
            bf16x8 af = *(const bf16x8*)&base[(m * 32 + c5) * 128 + (chunk << 3)];
            acc32[m] = __builtin_amdgcn_mfma_f32_32x32x16_bf16(af, bfr, acc32[m], 0, 0, 0);
        }
    }

    // ---- phase 2: per-channel softmax over k (exp2; log2e in wsA) + pooling
    // 32x32 C layout: col = c5, row = (reg&3) + 8*(reg>>2) + 4*hi.
    // Tile m covers points {2m, 2m+1}: regs 0..7 -> pt 2m, 8..15 -> pt 2m+1.
    // cat col c = w*32+c5: w<4 -> featS (c<128), w>=4 -> mlpS (c-128).
    {
        const int c = w * 32 + c5;
        const int cl = c & 127;
        const __hip_bfloat16* catBase = (w < 4) ? featS : mlpS;
        #pragma unroll
        for (int m = 0; m < 4; ++m) {
            float sA = 0.f, sB = 0.f, pA = 0.f, pB = 0.f;
            #pragma unroll
            for (int reg = 0; reg < 16; ++reg) {
                float e = __builtin_amdgcn_exp2f(acc32[m][reg]);
                int rowin = (reg & 3) + 8 * (reg >> 2) + 4 * hi;
                int cvo = ((((cl >> 3) ^ ((reg & 3) + 4 * hi)) << 3) + (cl & 7));
                float cv = __bfloat162float(catBase[(m * 32 + rowin) * 128 + cvo]);
                if (reg < 8) { sA += e; pA += e * cv; }
                else         { sB += e; pB += e * cv; }
            }
            sA += __shfl_xor(sA, 32);
            sB += __shfl_xor(sB, 32);
            pA += __shfl_xor(pA, 32);
            pB += __shfl_xor(pB, 32);
            if (hi == 0)
                a2S[(2 * m) * A2_LD + CIN + c] =
                    __float2bfloat16(pA * __builtin_amdgcn_rcpf(sA));
            else
                a2S[(2 * m + 1) * A2_LD + CIN + c] =
                    __float2bfloat16(pB * __builtin_amdgcn_rcpf(sB));
        }
    }
    __syncthreads();

    // ---- phase 3: out GEMM  [8 x 256] = [feat|pooled][8 x 384] @ W2[384 x 256]
    const f32x4 vzero = {0.f, 0.f, 0.f, 0.f};
    f32x4 acc2[2];
    acc2[0] = vzero; acc2[1] = vzero;
    #pragma unroll
    for (int kt = 0; kt < 12; ++kt) {
        bf16x8 a = *(const bf16x8*)&a2S[(c0 & 7) * A2_LD + kt * 32 + q * 8];
        bf16x8 b0 = *(const bf16x8*)(wsB + (size_t)(((kt * 16 + 2 * w + 0) * 64 + lane) * 8));
        bf16x8 b1 = *(const bf16x8*)(wsB + (size_t)(((kt * 16 + 2 * w + 1) * 64 + lane) * 8));
        acc2[0] = __builtin_amdgcn_mfma_f32_16x16x32_bf16(a, b0, acc2[0], 0, 0, 0);
        acc2[1] = __builtin_amdgcn_mfma_f32_16x16x32_bf16(a, b1, acc2[1], 0, 0, 0);
    }
    // stage to LDS (reuse featS as fp32 [8][256]), then fully-coalesced float4 store
    float* outS = (float*)featS;
    if (q < 2) {                       // rows q*4+r = points 0..7 exactly
        #pragma unroll
        for (int i = 0; i < 2; ++i) {
            int c = (2 * w + i) * 16 + c0;
            float dv = dd[c];
            #pragma unroll
            for (int r = 0; r < 4; ++r) {
                int p = q * 4 + r;
                float y = acc2[i][r] + dv;
                y = fmaxf(y, 0.2f * y);
                outS[p * 256 + c] = y;
            }
        }
    }
    __syncthreads();
    {
        int p = tid >> 6, c4 = (tid & 63) * 4;
        *(float4*)(out + (base0 + p) * COUT + c4) = *(const float4*)&outS[p * 256 + c4];
    }
}

extern "C" void kernel_launch(void* const* d_in, const int* in_sizes, int n_in,
                              void* d_out, int out_size, void* d_ws, size_t ws_size,
                              hipStream_t stream) {
    const float* feature = (const float*)d_in[0];
    const float* rawn    = (const float*)d_in[1];
    const int*   nidx    = (const int*)d_in[2];
    const float* w_n     = (const float*)d_in[3];
    const float* b_n     = (const float*)d_in[4];
    const float* g_n     = (const float*)d_in[5];
    const float* beta_n  = (const float*)d_in[6];
    const float* rm_n    = (const float*)d_in[7];
    const float* rv_n    = (const float*)d_in[8];
    const float* w_attn  = (const float*)d_in[9];
    const float* w_o     = (const float*)d_in[10];
    const float* b_o     = (const float*)d_in[11];
    const float* g_o     = (const float*)d_in[12];
    const float* beta_o  = (const float*)d_in[13];
    const float* rm_o    = (const float*)d_in[14];
    const float* rv_o    = (const float*)d_in[15];
    const float* w_s     = (const float*)d_in[16];
    const float* b_s     = (const float*)d_in[17];
    const float* g_s     = (const float*)d_in[18];
    const float* beta_s  = (const float*)d_in[19];
    const float* rm_s    = (const float*)d_in[20];
    const float* rv_s    = (const float*)d_in[21];
    float* out = (float*)d_out;

    __hip_bfloat16* wsA    = (__hip_bfloat16*)((char*)d_ws + WSA_OFF);
    __hip_bfloat16* wsB    = (__hip_bfloat16*)((char*)d_ws + WSB_OFF);
    float*          ddp    = (float*)((char*)d_ws + DD_OFF);
    __hip_bfloat16* wsN    = (__hip_bfloat16*)((char*)d_ws + WN_OFF);
    float*          dnw    = (float*)((char*)d_ws + DN_OFF);
    __hip_bfloat16* featbf = (__hip_bfloat16*)((char*)d_ws + FB_OFF);
    const int use_fb = (ws_size >= WS_FB) ? 1 : 0;

    lfa_pre<<<2132, 256, 0, stream>>>(
        feature, w_attn,
        w_n, b_n, g_n, beta_n, rm_n, rv_n,
        w_o, b_o, g_o, beta_o, rm_o, rv_o,
        w_s, b_s, g_s, beta_s, rm_s, rv_s,
        featbf, wsA, wsB, ddp, wsN, dnw, use_fb);

    const int nblocks = (4 * NPTS) / PB;   // 4096
    lfa_main<<<nblocks, 512, 0, stream>>>(
        feature, rawn, nidx,
        wsA, wsB, ddp, wsN, dnw, featbf, use_fb, out);
}